// Round 5
// baseline (214.745 us; speedup 1.0000x reference)
//
#include <hip/hip_runtime.h>

#define B_ 8
#define N_ 4096
#define C_ 512
#define H_ 8

typedef _Float16 h8  __attribute__((ext_vector_type(8)));
typedef _Float16 h4v __attribute__((ext_vector_type(4)));
typedef float    f4  __attribute__((ext_vector_type(4)));

// ---- workspace layout (bytes) ----
static const size_t OFF_COS  = 0;                                  // 4 MiB f32 [4096][256]
static const size_t OFF_SIN  = (size_t)4*1024*1024;                // 4 MiB
static const size_t OFF_KRH  = (size_t)8*1024*1024;                // 32 MiB f16 [B*N][C] k_rope
static const size_t OFF_WQH  = (size_t)40*1024*1024;               // 512 KiB f16
static const size_t OFF_WKH  = (size_t)40*1024*1024 + 512*1024;    // 512 KiB f16
static const size_t OFF_KSUM = (size_t)41*1024*1024;               // 16 KiB f32 [8][512] (64K slot)
static const size_t OFF_KVG  = (size_t)41*1024*1024 + 64*1024;     // 1 MiB f32 [64bh][64d][64e]
static const size_t OFF_KVT  = (size_t)42*1024*1024 + 64*1024;     // 512 KiB f16 [64bh][64e][64d]

__device__ __forceinline__ unsigned int pack2h(float a, float b){
    union { _Float16 h[2]; unsigned int u; } x;
    x.h[0] = (_Float16)a; x.h[1] = (_Float16)b; return x.u;
}

// ---- cos/sin tables ----
__global__ void k_tables(float* __restrict__ cosT, float* __restrict__ sinT){
    int n = blockIdx.x, j = threadIdx.x;
    double th = exp((double)j * -0.035977892078031970); // ln(1e4)/256
    float ang = (float)n * (float)th;
    float s, c; sincosf(ang, &s, &c);
    cosT[n*256 + j] = c; sinT[n*256 + j] = s;
}

// ---- weights f32 -> f16 ----
__global__ __launch_bounds__(256) void k_prepw(const float* __restrict__ Wq, const float* __restrict__ Wk,
                                               _Float16* __restrict__ Wqh, _Float16* __restrict__ Wkh){
    int u = blockIdx.x*256 + threadIdx.x;
    {
        float4 a = *(const float4*)&Wq[(size_t)u*8];
        float4 b = *(const float4*)&Wq[(size_t)u*8 + 4];
        uint4 o; o.x = pack2h(a.x,a.y); o.y = pack2h(a.z,a.w); o.z = pack2h(b.x,b.y); o.w = pack2h(b.z,b.w);
        *(uint4*)&Wqh[(size_t)u*8] = o;
    }
    {
        float4 a = *(const float4*)&Wk[(size_t)u*8];
        float4 b = *(const float4*)&Wk[(size_t)u*8 + 4];
        uint4 o; o.x = pack2h(a.x,a.y); o.y = pack2h(a.z,a.w); o.z = pack2h(b.x,b.y); o.w = pack2h(b.z,b.w);
        *(uint4*)&Wkh[(size_t)u*8] = o;
    }
}

// ---- stage 128x32 f16 tile via global_load_lds, swizzled source / linear dest ----
__device__ __forceinline__ void stage_b(const _Float16* __restrict__ g, _Float16* lds, int t){
#pragma unroll
    for (int i=0;i<2;++i){
        int u = i*256 + t;
        int r = u >> 2;
        int c8 = (u & 3) ^ ((r ^ (r >> 2)) & 3);
        __builtin_amdgcn_global_load_lds(
            (const __attribute__((address_space(1))) void*)(g + (size_t)r*C_ + c8*8),
            (__attribute__((address_space(3))) void*)(lds + (size_t)(i*256 + (t & 192))*8),
            16, 0, 0);
    }
}

// ---- fused GEMM: IS_Q=0: k path (-> krh, ksum); IS_Q=1: q path (fused z, qr@kv, lepe, out) ----
template<int IS_Q>
__global__ __launch_bounds__(256, IS_Q ? 3 : 4) void k_gemm(
    const float* __restrict__ X, const _Float16* __restrict__ Wh, const float* __restrict__ bias,
    const float* __restrict__ cosT, const float* __restrict__ sinT,
    _Float16* __restrict__ krh, float* __restrict__ ksum,
    const float* __restrict__ ksumIn, const _Float16* __restrict__ kvTg,
    const float* __restrict__ y, const float* __restrict__ lw, const float* __restrict__ lb,
    float* __restrict__ outp)
{
    __shared__ __align__(16) char smem[IS_Q ? 53248 : 36864];
    _Float16* qrs = (_Float16*)smem;              // alias (epilogue): 4 waves x [64][72] f16
    _Float16* kvs = (_Float16*)(smem + 36864);    // (IS_Q) 2 heads x [64][64] f16, unit-XOR swizzled

    const int t = threadIdx.x;
    const int lane = t & 63;
    const int w = t >> 6;
    const int wm = w >> 1, wn = w & 1;
    const int col0 = blockIdx.x * 128;
    const int row0 = blockIdx.y * 128;
    const int lrow = lane & 15, lg = lane >> 4;
    const int srow = t >> 3;
    const int sc4 = (t & 7) * 4;
    const int b = row0 >> 12;

    f4 acc[4][4] = {};
    const float* Xp = X + (size_t)(row0 + srow)*C_ + sc4;
    float4 ra[4];
#pragma unroll
    for (int it=0; it<4; ++it) ra[it] = *(const float4*)(Xp + (size_t)it*32*C_);
    stage_b(Wh + (size_t)col0*C_, (_Float16*)(smem + 20480), t);

    const int sw = (lrow ^ (lrow >> 2)) & 3;
    const int cB = (lg ^ sw) * 8;
    int cur = 0;

    for (int kk=0; kk<16; ++kk){
        _Float16* As = (_Float16*)(smem + cur*10240);
#pragma unroll
        for (int it=0; it<4; ++it){
            int r = srow + it*32;
            h4v a; a[0]=(_Float16)ra[it].x; a[1]=(_Float16)ra[it].y; a[2]=(_Float16)ra[it].z; a[3]=(_Float16)ra[it].w;
            *(h4v*)&As[r*40 + sc4] = a;
        }
        __syncthreads();
        if (kk < 15){
#pragma unroll
            for (int it=0; it<4; ++it)
                ra[it] = *(const float4*)(Xp + (size_t)it*32*C_ + (kk+1)*32);
            stage_b(Wh + (size_t)col0*C_ + (kk+1)*32, (_Float16*)(smem + 20480 + (cur^1)*8192), t);
        }
        _Float16* Bs = (_Float16*)(smem + 20480 + cur*8192);
        h8 af[4], bf[4];
#pragma unroll
        for (int mi=0; mi<4; ++mi) af[mi] = *(const h8*)&As[(wm*64 + mi*16 + lrow)*40 + lg*8];
#pragma unroll
        for (int ni=0; ni<4; ++ni) bf[ni] = *(const h8*)&Bs[(wn*64 + ni*16 + lrow)*32 + cB];
#pragma unroll
        for (int mi=0; mi<4; ++mi)
#pragma unroll
            for (int ni=0; ni<4; ++ni)
                acc[mi][ni] = __builtin_amdgcn_mfma_f32_16x16x32_f16(af[mi], bf[ni], acc[mi][ni], 0,0,0);
        cur ^= 1;
    }
    __syncthreads();   // LDS fully free past here

    // ---- epilogue ----
    const int hcol0 = col0 + wn*64;
    if constexpr (IS_Q){
        // stage kv tiles for this block's two heads (XOR-swizzled units), overlaps VALU below
#pragma unroll
        for (int i=0;i<4;++i){
            int idx = i*256 + t;
            int hl = idx >> 9, e = (idx >> 3) & 63, u = idx & 7;
            int du = u ^ (e & 7);
            int bhh = b*H_ + (col0 >> 6) + hl;
            *(uint4*)&kvs[hl*4096 + e*64 + u*8] =
                *(const uint4*)&kvTg[(size_t)bhh*4096 + e*64 + du*8];
        }
    }
    float bcol[4], km[4];
#pragma unroll
    for (int ni=0; ni<4; ++ni){
        int c = hcol0 + ni*16 + lrow;
        bcol[ni] = bias[c];
        km[ni] = IS_Q ? ksumIn[b*C_ + c] * (1.0f/4096.0f) : 0.0f;
    }
    float colsum[4] = {0.f,0.f,0.f,0.f};
    float zr[4][4];
    _Float16* qw = qrs + w*4608;   // wave-local [64][72]

#pragma unroll
    for (int mi=0; mi<4; ++mi){
        float qv[4][4];
#pragma unroll
        for (int ni=0; ni<4; ++ni)
#pragma unroll
            for (int r=0; r<4; ++r){
                float v = acc[mi][ni][r] + bcol[ni];
                qv[ni][r] = v > 0.f ? v + 1.f : __expf(v);   // elu+1
            }
        if constexpr (IS_Q){
#pragma unroll
            for (int r=0; r<4; ++r){
                float p = qv[0][r]*km[0] + qv[1][r]*km[1] + qv[2][r]*km[2] + qv[3][r]*km[3];
                p += __shfl_xor(p, 1); p += __shfl_xor(p, 2);
                p += __shfl_xor(p, 4); p += __shfl_xor(p, 8);
                zr[mi][r] = 1.0f / (p + 1e-6f);
            }
        } else {
#pragma unroll
            for (int ni=0; ni<4; ++ni)
                colsum[ni] += qv[ni][0]+qv[ni][1]+qv[ni][2]+qv[ni][3];
        }
        // rope
#pragma unroll
        for (int ni=0; ni<4; ++ni){
            int c = hcol0 + ni*16 + lrow;
            int jj = c >> 1;
#pragma unroll
            for (int r=0; r<4; ++r){
                int grow = row0 + wm*64 + mi*16 + lg*4 + r;
                int n = grow & (N_-1);
                float val = qv[ni][r];
                float par = __shfl_xor(val, 1);
                float cs = cosT[n*256 + jj], sn = sinT[n*256 + jj];
                float rv = (lane & 1) ? fmaf(sn, par, cs*val) : fmaf(cs, val, -sn*par);
                float prv = __shfl_xor(rv, 1);
                if constexpr (IS_Q){
                    if (!(lane & 1))
                        *(unsigned int*)&qw[(mi*16 + lg*4 + r)*72 + (ni*16 + lrow)] = pack2h(rv, prv);
                } else {
                    if (!(lane & 1))
                        *(unsigned int*)&krh[(size_t)grow*C_ + c] = pack2h(rv, prv);
                }
            }
        }
    }

    if constexpr (!IS_Q){
#pragma unroll
        for (int ni=0; ni<4; ++ni){
            float s = colsum[ni];
            s += __shfl_xor(s, 16); s += __shfl_xor(s, 32);
            if (lane < 16) atomicAdd(&ksum[b*C_ + hcol0 + ni*16 + lane], s);
        }
    } else {
        __syncthreads();   // qrs + kvs ready
        // wave-local out-gemm: out[64n x 64e] = qr(64x64) @ kv(64x64)
        f4 acc2[4][4] = {};
#pragma unroll
        for (int ks=0; ks<2; ++ks){
            h8 af2[4], bf2[4];
#pragma unroll
            for (int mi2=0; mi2<4; ++mi2) af2[mi2] = *(const h8*)&qw[(mi2*16 + lrow)*72 + ks*32 + lg*8];
#pragma unroll
            for (int ni2=0; ni2<4; ++ni2){
                int e = ni2*16 + lrow;
                int du = ((ks*4 + lg) ^ (e & 7)) * 8;
                bf2[ni2] = *(const h8*)&kvs[wn*4096 + e*64 + du];
            }
#pragma unroll
            for (int mi2=0; mi2<4; ++mi2)
#pragma unroll
                for (int ni2=0; ni2<4; ++ni2)
                    acc2[mi2][ni2] = __builtin_amdgcn_mfma_f32_16x16x32_f16(af2[mi2], bf2[ni2], acc2[mi2][ni2], 0,0,0);
        }
        // z-scale, write back f16 into own qw tile
#pragma unroll
        for (int mi2=0; mi2<4; ++mi2){
#pragma unroll
            for (int r=0; r<4; ++r){
                float z = zr[mi2][r];
#pragma unroll
                for (int ni2=0; ni2<4; ++ni2){
                    float val = acc2[mi2][ni2][r] * z;
                    float pv = __shfl_xor(val, 1);
                    if (!(lane & 1))
                        *(unsigned int*)&qw[(mi2*16 + lg*4 + r)*72 + (ni2*16 + lrow)] = pack2h(val, pv);
                }
            }
        }
        __syncthreads();
        // row-major remap: lepe + out, fully coalesced
        const int cg = t & 31;          // col group (4 floats)
        const int c4p = cg * 4;
        const int hl = c4p >> 6;
        const int e0 = c4p & 63;
        float w0[4], w1[4], w2[4], wb[4];
#pragma unroll
        for (int j=0;j<4;++j){
            int cc = col0 + c4p + j;
            w0[j]=lw[cc*3+0]; w1[j]=lw[cc*3+1]; w2[j]=lw[cc*3+2]; wb[j]=lb[cc];
        }
#pragma unroll
        for (int i=0;i<16;++i){
            int rl = (t >> 5) + i*8;
            int grow = row0 + rl;
            int nloc = grow & (N_-1);
            int wreg = (rl >> 6)*2 + hl;
            h4v a = *(const h4v*)&qrs[wreg*4608 + (rl & 63)*72 + e0];
            const float* yp = y + (size_t)grow*C_ + col0 + c4p;
            float4 y1 = *(const float4*)yp;
            float s0 = fmaf(y1.x, w1[0], wb[0]);
            float s1 = fmaf(y1.y, w1[1], wb[1]);
            float s2 = fmaf(y1.z, w1[2], wb[2]);
            float s3 = fmaf(y1.w, w1[3], wb[3]);
            if (nloc > 0){
                float4 y0 = *(const float4*)(yp - C_);
                s0 = fmaf(y0.x, w0[0], s0); s1 = fmaf(y0.y, w0[1], s1);
                s2 = fmaf(y0.z, w0[2], s2); s3 = fmaf(y0.w, w0[3], s3);
            }
            if (nloc < N_-1){
                float4 y2 = *(const float4*)(yp + C_);
                s0 = fmaf(y2.x, w2[0], s0); s1 = fmaf(y2.y, w2[1], s1);
                s2 = fmaf(y2.z, w2[2], s2); s3 = fmaf(y2.w, w2[3], s3);
            }
            float4 o;
            o.x = (float)a[0] + s0; o.y = (float)a[1] + s1;
            o.z = (float)a[2] + s2; o.w = (float)a[3] + s3;
            *(float4*)&outp[(size_t)grow*C_ + col0 + c4p] = o;
        }
    }
}

// ---- kv = (1/N) k_rope^T @ v : LDS-transposed tiles, chunk-XOR swizzle, atomic f32 partials ----
__global__ __launch_bounds__(256) void k_kv(const _Float16* __restrict__ krh, const float* __restrict__ y,
                                            float* __restrict__ kvg){
    __shared__ _Float16 krs[64*128];
    __shared__ _Float16 vs[64*128];
    const int split = blockIdx.x, bh = blockIdx.y;
    const int b = bh >> 3, h = bh & 7;
    const int t = threadIdx.x, lane = t & 63, w = t >> 6;
    const int lrow = lane & 15, lg = lane >> 4;
    f4 acc[4] = {};
    for (int sub=0; sub<4; ++sub){
        const int n0 = split*512 + sub*128;
#pragma unroll
        for (int i=0;i<8;++i){
            int q = i*256 + t;
            int d2 = q & 31, n2 = q >> 5;
            int n = n0 + 2*n2, c = h*64 + 2*d2;
            size_t g0 = (size_t)(b*N_ + n)*C_ + c;
            unsigned int u0 = *(const unsigned int*)&krh[g0];
            unsigned int u1 = *(const unsigned int*)&krh[g0 + C_];
            int chunk = n2 >> 2, j2 = (n2 & 3)*2;
            int pc0 = chunk ^ ((2*d2) & 15);
            int pc1 = pc0 ^ 1;
            *(unsigned int*)&krs[(2*d2)*128 + pc0*8 + j2]   = (u0 & 0xffffu) | (u1 << 16);
            *(unsigned int*)&krs[(2*d2+1)*128 + pc1*8 + j2] = (u0 >> 16) | (u1 & 0xffff0000u);
            float2 a0 = *(const float2*)&y[g0];
            float2 a1 = *(const float2*)&y[g0 + C_];
            *(unsigned int*)&vs[(2*d2)*128 + pc0*8 + j2]   = pack2h(a0.x, a1.x);
            *(unsigned int*)&vs[(2*d2+1)*128 + pc1*8 + j2] = pack2h(a0.y, a1.y);
        }
        __syncthreads();
#pragma unroll
        for (int ks=0; ks<4; ++ks){
            int cu = ((ks*4 + lg) ^ lrow)*8;
            h8 a = *(const h8*)&krs[(w*16 + lrow)*128 + cu];
#pragma unroll
            for (int ni=0; ni<4; ++ni){
                h8 bv = *(const h8*)&vs[(ni*16 + lrow)*128 + cu];
                acc[ni] = __builtin_amdgcn_mfma_f32_16x16x32_f16(a, bv, acc[ni], 0,0,0);
            }
        }
        __syncthreads();
    }
#pragma unroll
    for (int ni=0; ni<4; ++ni)
#pragma unroll
        for (int rr=0; rr<4; ++rr)
            atomicAdd(&kvg[(size_t)bh*4096 + (w*16 + lg*4 + rr)*64 + ni*16 + lrow],
                      acc[ni][rr] * (1.0f/4096.0f));
}

// ---- kvg f32 [bh][d][e] -> kvTg f16 [bh][e][d] ----
__global__ __launch_bounds__(256) void k_kvmerge(const float* __restrict__ kvg, _Float16* __restrict__ kvTg){
    int bh = blockIdx.x, t = threadIdx.x;
    const float* src = kvg + (size_t)bh*4096;
    _Float16* dst = kvTg + (size_t)bh*4096;
#pragma unroll
    for (int i=0;i<4;++i){
        int q = i*256 + t;
        int e2 = q & 31, d2 = q >> 5;
        float2 a0 = *(const float2*)&src[(2*d2)*64 + 2*e2];
        float2 a1 = *(const float2*)&src[(2*d2+1)*64 + 2*e2];
        *(unsigned int*)&dst[(2*e2)*64 + 2*d2]   = pack2h(a0.x, a1.x);
        *(unsigned int*)&dst[(2*e2+1)*64 + 2*d2] = pack2h(a0.y, a1.y);
    }
}

extern "C" void kernel_launch(void* const* d_in, const int* in_sizes, int n_in,
                              void* d_out, int out_size, void* d_ws, size_t ws_size,
                              hipStream_t stream)
{
    (void)in_sizes; (void)n_in; (void)out_size; (void)ws_size;
    const float* x  = (const float*)d_in[0];
    const float* y  = (const float*)d_in[1];
    const float* Wq = (const float*)d_in[2];
    const float* bq = (const float*)d_in[3];
    const float* Wk = (const float*)d_in[4];
    const float* bk = (const float*)d_in[5];
    const float* lw = (const float*)d_in[6];
    const float* lb = (const float*)d_in[7];

    char* ws = (char*)d_ws;
    float*    cosT = (float*)(ws + OFF_COS);
    float*    sinT = (float*)(ws + OFF_SIN);
    _Float16* krh  = (_Float16*)(ws + OFF_KRH);
    _Float16* Wqh  = (_Float16*)(ws + OFF_WQH);
    _Float16* Wkh  = (_Float16*)(ws + OFF_WKH);
    float*    ksum = (float*)(ws + OFF_KSUM);
    float*    kvg  = (float*)(ws + OFF_KVG);
    _Float16* kvTg = (_Float16*)(ws + OFF_KVT);
    float*    out  = (float*)d_out;

    hipMemsetAsync(ws + OFF_KSUM, 0, 64*1024 + 1024*1024, stream);
    k_tables<<<dim3(N_), dim3(256), 0, stream>>>(cosT, sinT);
    k_prepw<<<dim3(128), dim3(256), 0, stream>>>(Wq, Wk, Wqh, Wkh);
    k_gemm<0><<<dim3(4, 256), dim3(256), 0, stream>>>(y, Wkh, bk, cosT, sinT,
        krh, ksum, nullptr, nullptr, nullptr, nullptr, nullptr, nullptr);
    k_kv<<<dim3(8, 64), dim3(256), 0, stream>>>(krh, y, kvg);
    k_kvmerge<<<dim3(64), dim3(256), 0, stream>>>(kvg, kvTg);
    k_gemm<1><<<dim3(4, 256), dim3(256), 0, stream>>>(x, Wqh, bq, cosT, sinT,
        nullptr, nullptr, ksum, kvTg, y, lw, lb, out);
}

// Round 6
// 210.653 us; speedup vs baseline: 1.0194x; 1.0194x over previous
//
#include <hip/hip_runtime.h>

#define B_ 8
#define N_ 4096
#define C_ 512
#define H_ 8

typedef _Float16 h8  __attribute__((ext_vector_type(8)));
typedef _Float16 h4v __attribute__((ext_vector_type(4)));
typedef float    f4  __attribute__((ext_vector_type(4)));

// ---- workspace layout (bytes), peak ~74.6 MiB (proven budget >=82 MiB) ----
static const size_t OFF_COS  = 0;                                  // 4 MiB f32 [4096][256]
static const size_t OFF_SIN  = (size_t)4*1024*1024;                // 4 MiB
static const size_t OFF_KRH  = (size_t)8*1024*1024;                // 32 MiB f16 [B*N][C]: krh, later reused as xh
static const size_t OFF_YH   = (size_t)40*1024*1024;               // 32 MiB f16 [B*N][C]
static const size_t OFF_WQH  = (size_t)72*1024*1024;               // 512 KiB f16
static const size_t OFF_WKH  = (size_t)72*1024*1024 + 512*1024;    // 512 KiB f16
static const size_t OFF_KSUM = (size_t)73*1024*1024;               // 16 KiB f32 (64K slot)
static const size_t OFF_KVG  = (size_t)73*1024*1024 + 64*1024;     // 1 MiB f32 [64bh][64d][64e]
static const size_t OFF_KVT  = (size_t)74*1024*1024 + 64*1024;     // 512 KiB f16 [64bh][64e][64d]

__device__ __forceinline__ unsigned int pack2h(float a, float b){
    union { _Float16 h[2]; unsigned int u; } x;
    x.h[0] = (_Float16)a; x.h[1] = (_Float16)b; return x.u;
}

// ---- cos/sin tables ----
__global__ void k_tables(float* __restrict__ cosT, float* __restrict__ sinT){
    int n = blockIdx.x, j = threadIdx.x;
    double th = exp((double)j * -0.035977892078031970); // ln(1e4)/256
    float ang = (float)n * (float)th;
    float s, c; sincosf(ang, &s, &c);
    cosT[n*256 + j] = c; sinT[n*256 + j] = s;
}

// ---- f32 -> f16 streaming converts: y + Wq + Wk ----
__global__ __launch_bounds__(256) void k_prep_y(
    const float* __restrict__ y, const float* __restrict__ Wq, const float* __restrict__ Wk,
    _Float16* __restrict__ yh, _Float16* __restrict__ Wqh, _Float16* __restrict__ Wkh)
{
    int bid = blockIdx.x;
    const float* src; _Float16* dst; size_t base;
    if (bid < 8192)      { src = y;  dst = yh;  base = (size_t)bid*2048; }
    else if (bid < 8320) { src = Wq; dst = Wqh; base = (size_t)(bid-8192)*2048; }
    else                 { src = Wk; dst = Wkh; base = (size_t)(bid-8320)*2048; }
    size_t o = base + (size_t)threadIdx.x*8;
    float4 a = *(const float4*)&src[o];
    float4 b = *(const float4*)&src[o+4];
    uint4 r; r.x = pack2h(a.x,a.y); r.y = pack2h(a.z,a.w); r.z = pack2h(b.x,b.y); r.w = pack2h(b.z,b.w);
    *(uint4*)&dst[o] = r;
}

// ---- x -> f16 (into the retired krh region) ----
__global__ __launch_bounds__(256) void k_prep_x(const float* __restrict__ x, _Float16* __restrict__ xh){
    size_t o = (size_t)blockIdx.x*2048 + (size_t)threadIdx.x*8;
    float4 a = *(const float4*)&x[o];
    float4 b = *(const float4*)&x[o+4];
    uint4 r; r.x = pack2h(a.x,a.y); r.y = pack2h(a.z,a.w); r.z = pack2h(b.x,b.y); r.w = pack2h(b.z,b.w);
    *(uint4*)&xh[o] = r;
}

// ---- stage 128x32 f16 tile via global_load_lds; linear dest, source pre-swizzled ----
// phys 16B-unit p = r*4 + (j ^ s(r)), s(r) = (r ^ (r>>2)) & 3
__device__ __forceinline__ void stage_tile(const _Float16* __restrict__ g, _Float16* lds, int t){
#pragma unroll
    for (int i=0;i<2;++i){
        int u = i*256 + t;
        int r = u >> 2;
        int j = (u & 3) ^ ((r ^ (r >> 2)) & 3);
        __builtin_amdgcn_global_load_lds(
            (const __attribute__((address_space(1))) void*)(g + (size_t)r*C_ + j*8),
            (__attribute__((address_space(3))) void*)(lds + (size_t)(i*256 + (t & 192))*8),
            16, 0, 0);
    }
}

// ---- fused GEMM, m97-shape: both operands via global_load_lds, 2 barriers/K-step ----
// IS_Q=0: k path (-> krh, ksum); IS_Q=1: q path (fused z, qr@kv, lepe, coalesced out)
template<int IS_Q>
__global__ __launch_bounds__(256, IS_Q ? 3 : 4) void k_gemm(
    const _Float16* __restrict__ A, const _Float16* __restrict__ Wh, const float* __restrict__ bias,
    const float* __restrict__ cosT, const float* __restrict__ sinT,
    _Float16* __restrict__ krh, float* __restrict__ ksum,
    const float* __restrict__ ksumIn, const _Float16* __restrict__ kvTg,
    const _Float16* __restrict__ yh, const float* __restrict__ lw, const float* __restrict__ lb,
    float* __restrict__ outp)
{
    // main: As@0 (2x8192), Bs@16384 (2x8192). epilogue(Q): qrs@0 (36864), kvs@36864 (16384)
    __shared__ __align__(16) char smem[IS_Q ? 53248 : 32768];
    _Float16* qrs = (_Float16*)smem;
    _Float16* kvs = (_Float16*)(smem + 36864);

    const int t = threadIdx.x;
    const int lane = t & 63;
    const int w = t >> 6;
    const int wm = w >> 1, wn = w & 1;
    const int col0 = blockIdx.x * 128;
    const int row0 = blockIdx.y * 128;
    const int lrow = lane & 15, lg = lane >> 4;
    const int b = row0 >> 12;

    if constexpr (IS_Q){
        // prefetch kv tiles for this block's two heads (latency hidden under main loop)
#pragma unroll
        for (int i=0;i<4;++i){
            int idx = i*256 + t;
            int hl = idx >> 9, w9 = idx & 511, e = w9 >> 3, u8 = w9 & 7;
            int j = u8 ^ (e & 7);
            int bhh = b*H_ + (col0 >> 6) + hl;
            __builtin_amdgcn_global_load_lds(
                (const __attribute__((address_space(1))) void*)(kvTg + (size_t)bhh*4096 + e*64 + j*8),
                (__attribute__((address_space(3))) void*)(kvs + (size_t)(i*256 + (t & 192))*8),
                16, 0, 0);
        }
    }

    f4 acc[4][4] = {};
    stage_tile(A  + (size_t)row0*C_, (_Float16*)(smem), t);
    stage_tile(Wh + (size_t)col0*C_, (_Float16*)(smem + 16384), t);

    const int sw = (lrow ^ (lrow >> 2)) & 3;
    const int cK = (lg ^ sw) * 8;
    int cur = 0;

    for (int kk=0; kk<16; ++kk){
        __syncthreads();   // staged tile [cur] ready (vmcnt drained here)
        if (kk < 15){
            stage_tile(A  + (size_t)row0*C_ + (kk+1)*32, (_Float16*)(smem + (cur^1)*8192), t);
            stage_tile(Wh + (size_t)col0*C_ + (kk+1)*32, (_Float16*)(smem + 16384 + (cur^1)*8192), t);
        }
        const _Float16* As = (const _Float16*)(smem + cur*8192);
        const _Float16* Bs = (const _Float16*)(smem + 16384 + cur*8192);
        h8 af[4], bf[4];
#pragma unroll
        for (int mi=0; mi<4; ++mi) af[mi] = *(const h8*)&As[(wm*64 + mi*16 + lrow)*32 + cK];
#pragma unroll
        for (int ni=0; ni<4; ++ni) bf[ni] = *(const h8*)&Bs[(wn*64 + ni*16 + lrow)*32 + cK];
#pragma unroll
        for (int mi=0; mi<4; ++mi)
#pragma unroll
            for (int ni=0; ni<4; ++ni)
                acc[mi][ni] = __builtin_amdgcn_mfma_f32_16x16x32_f16(af[mi], bf[ni], acc[mi][ni], 0,0,0);
        __syncthreads();   // reads of [cur] done before next iter overwrites it
        cur ^= 1;
    }

    // ---- epilogue ----
    const int hcol0 = col0 + wn*64;
    float bcol[4], km[4];
#pragma unroll
    for (int ni=0; ni<4; ++ni){
        int c = hcol0 + ni*16 + lrow;
        bcol[ni] = bias[c];
        km[ni] = IS_Q ? ksumIn[b*C_ + c] * (1.0f/4096.0f) : 0.0f;
    }
    float colsum[4] = {0.f,0.f,0.f,0.f};
    float zr[4][4];
    _Float16* qw = qrs + w*4608;   // wave-local [64][72]

#pragma unroll
    for (int mi=0; mi<4; ++mi){
        float qv[4][4];
#pragma unroll
        for (int ni=0; ni<4; ++ni)
#pragma unroll
            for (int r=0; r<4; ++r){
                float v = acc[mi][ni][r] + bcol[ni];
                qv[ni][r] = v > 0.f ? v + 1.f : __expf(v);   // elu+1
            }
        if constexpr (IS_Q){
#pragma unroll
            for (int r=0; r<4; ++r){
                float p = qv[0][r]*km[0] + qv[1][r]*km[1] + qv[2][r]*km[2] + qv[3][r]*km[3];
                p += __shfl_xor(p, 1); p += __shfl_xor(p, 2);
                p += __shfl_xor(p, 4); p += __shfl_xor(p, 8);
                zr[mi][r] = 1.0f / (p + 1e-6f);
            }
        } else {
#pragma unroll
            for (int ni=0; ni<4; ++ni)
                colsum[ni] += qv[ni][0]+qv[ni][1]+qv[ni][2]+qv[ni][3];
        }
        // rope
#pragma unroll
        for (int ni=0; ni<4; ++ni){
            int c = hcol0 + ni*16 + lrow;
            int jj = c >> 1;
#pragma unroll
            for (int r=0; r<4; ++r){
                int grow = row0 + wm*64 + mi*16 + lg*4 + r;
                int n = grow & (N_-1);
                float val = qv[ni][r];
                float par = __shfl_xor(val, 1);
                float cs = cosT[n*256 + jj], sn = sinT[n*256 + jj];
                float rv = (lane & 1) ? fmaf(sn, par, cs*val) : fmaf(cs, val, -sn*par);
                float prv = __shfl_xor(rv, 1);
                if constexpr (IS_Q){
                    if (!(lane & 1))
                        *(unsigned int*)&qw[(mi*16 + lg*4 + r)*72 + (ni*16 + lrow)] = pack2h(rv, prv);
                } else {
                    if (!(lane & 1))
                        *(unsigned int*)&krh[(size_t)grow*C_ + c] = pack2h(rv, prv);
                }
            }
        }
    }

    if constexpr (!IS_Q){
#pragma unroll
        for (int ni=0; ni<4; ++ni){
            float s = colsum[ni];
            s += __shfl_xor(s, 16); s += __shfl_xor(s, 32);
            if (lane < 16) atomicAdd(&ksum[b*C_ + hcol0 + ni*16 + lane], s);
        }
    } else {
        __syncthreads();   // qrs written by all waves; kvs prefetch long since drained
        // wave-local out-gemm: out[64n x 64e] = qr(64x64) @ kv(64x64)
        f4 acc2[4][4] = {};
#pragma unroll
        for (int ks=0; ks<2; ++ks){
            h8 af2[4], bf2[4];
#pragma unroll
            for (int mi2=0; mi2<4; ++mi2) af2[mi2] = *(const h8*)&qw[(mi2*16 + lrow)*72 + ks*32 + lg*8];
#pragma unroll
            for (int ni2=0; ni2<4; ++ni2){
                int e = ni2*16 + lrow;
                int du = ((ks*4 + lg) ^ (e & 7)) * 8;
                bf2[ni2] = *(const h8*)&kvs[wn*4096 + e*64 + du];
            }
#pragma unroll
            for (int mi2=0; mi2<4; ++mi2)
#pragma unroll
                for (int ni2=0; ni2<4; ++ni2)
                    acc2[mi2][ni2] = __builtin_amdgcn_mfma_f32_16x16x32_f16(af2[mi2], bf2[ni2], acc2[mi2][ni2], 0,0,0);
        }
        // z-scale, write back f16 into own qw tile
#pragma unroll
        for (int mi2=0; mi2<4; ++mi2){
#pragma unroll
            for (int r=0; r<4; ++r){
                float z = zr[mi2][r];
#pragma unroll
                for (int ni2=0; ni2<4; ++ni2){
                    float val = acc2[mi2][ni2][r] * z;
                    float pv = __shfl_xor(val, 1);
                    if (!(lane & 1))
                        *(unsigned int*)&qw[(mi2*16 + lg*4 + r)*72 + (ni2*16 + lrow)] = pack2h(val, pv);
                }
            }
        }
        __syncthreads();
        // row-major remap: lepe (reads yh) + out, fully coalesced
        const int cg = t & 31;
        const int c4p = cg * 4;
        const int hl = c4p >> 6;
        const int e0 = c4p & 63;
        float w0[4], w1[4], w2[4], wb[4];
#pragma unroll
        for (int j=0;j<4;++j){
            int cc = col0 + c4p + j;
            w0[j]=lw[cc*3+0]; w1[j]=lw[cc*3+1]; w2[j]=lw[cc*3+2]; wb[j]=lb[cc];
        }
#pragma unroll
        for (int i=0;i<16;++i){
            int rl = (t >> 5) + i*8;
            int grow = row0 + rl;
            int nloc = grow & (N_-1);
            int wreg = (rl >> 6)*2 + hl;
            h4v a = *(const h4v*)&qrs[wreg*4608 + (rl & 63)*72 + e0];
            const _Float16* yp = yh + (size_t)grow*C_ + col0 + c4p;
            h4v y1 = *(const h4v*)yp;
            float s0 = fmaf((float)y1[0], w1[0], wb[0]);
            float s1 = fmaf((float)y1[1], w1[1], wb[1]);
            float s2 = fmaf((float)y1[2], w1[2], wb[2]);
            float s3 = fmaf((float)y1[3], w1[3], wb[3]);
            if (nloc > 0){
                h4v y0 = *(const h4v*)(yp - C_);
                s0 = fmaf((float)y0[0], w0[0], s0); s1 = fmaf((float)y0[1], w0[1], s1);
                s2 = fmaf((float)y0[2], w0[2], s2); s3 = fmaf((float)y0[3], w0[3], s3);
            }
            if (nloc < N_-1){
                h4v y2 = *(const h4v*)(yp + C_);
                s0 = fmaf((float)y2[0], w2[0], s0); s1 = fmaf((float)y2[1], w2[1], s1);
                s2 = fmaf((float)y2[2], w2[2], s2); s3 = fmaf((float)y2[3], w2[3], s3);
            }
            float4 o;
            o.x = (float)a[0] + s0; o.y = (float)a[1] + s1;
            o.z = (float)a[2] + s2; o.w = (float)a[3] + s3;
            *(float4*)&outp[(size_t)grow*C_ + col0 + c4p] = o;
        }
    }
}

// ---- kv = (1/N) k_rope^T @ v : both operands f16, LDS-transposed, chunk-XOR swizzle ----
__global__ __launch_bounds__(256) void k_kv(const _Float16* __restrict__ krh, const _Float16* __restrict__ yh,
                                            float* __restrict__ kvg){
    __shared__ _Float16 krs[64*128];
    __shared__ _Float16 vs[64*128];
    const int split = blockIdx.x, bh = blockIdx.y;
    const int b = bh >> 3, h = bh & 7;
    const int t = threadIdx.x, lane = t & 63, w = t >> 6;
    const int lrow = lane & 15, lg = lane >> 4;
    f4 acc[4] = {};
    for (int sub=0; sub<4; ++sub){
        const int n0 = split*512 + sub*128;
#pragma unroll
        for (int i=0;i<8;++i){
            int q = i*256 + t;
            int d2 = q & 31, n2 = q >> 5;
            int n = n0 + 2*n2, c = h*64 + 2*d2;
            size_t g0 = (size_t)(b*N_ + n)*C_ + c;
            unsigned int u0 = *(const unsigned int*)&krh[g0];
            unsigned int u1 = *(const unsigned int*)&krh[g0 + C_];
            unsigned int v0 = *(const unsigned int*)&yh[g0];
            unsigned int v1 = *(const unsigned int*)&yh[g0 + C_];
            int chunk = n2 >> 2, j2 = (n2 & 3)*2;
            int pc0 = chunk ^ ((2*d2) & 15);
            int pc1 = pc0 ^ 1;
            *(unsigned int*)&krs[(2*d2)*128 + pc0*8 + j2]   = (u0 & 0xffffu) | (u1 << 16);
            *(unsigned int*)&krs[(2*d2+1)*128 + pc1*8 + j2] = (u0 >> 16) | (u1 & 0xffff0000u);
            *(unsigned int*)&vs[(2*d2)*128 + pc0*8 + j2]    = (v0 & 0xffffu) | (v1 << 16);
            *(unsigned int*)&vs[(2*d2+1)*128 + pc1*8 + j2]  = (v0 >> 16) | (v1 & 0xffff0000u);
        }
        __syncthreads();
#pragma unroll
        for (int ks=0; ks<4; ++ks){
            int cu = ((ks*4 + lg) ^ lrow)*8;
            h8 a = *(const h8*)&krs[(w*16 + lrow)*128 + cu];
#pragma unroll
            for (int ni=0; ni<4; ++ni){
                h8 bv = *(const h8*)&vs[(ni*16 + lrow)*128 + cu];
                acc[ni] = __builtin_amdgcn_mfma_f32_16x16x32_f16(a, bv, acc[ni], 0,0,0);
            }
        }
        __syncthreads();
    }
#pragma unroll
    for (int ni=0; ni<4; ++ni)
#pragma unroll
        for (int rr=0; rr<4; ++rr)
            atomicAdd(&kvg[(size_t)bh*4096 + (w*16 + lg*4 + rr)*64 + ni*16 + lrow],
                      acc[ni][rr] * (1.0f/4096.0f));
}

// ---- kvg f32 [bh][d][e] -> kvTg f16 [bh][e][d] ----
__global__ __launch_bounds__(256) void k_kvmerge(const float* __restrict__ kvg, _Float16* __restrict__ kvTg){
    int bh = blockIdx.x, t = threadIdx.x;
    const float* src = kvg + (size_t)bh*4096;
    _Float16* dst = kvTg + (size_t)bh*4096;
#pragma unroll
    for (int i=0;i<4;++i){
        int q = i*256 + t;
        int e2 = q & 31, d2 = q >> 5;
        float2 a0 = *(const float2*)&src[(2*d2)*64 + 2*e2];
        float2 a1 = *(const float2*)&src[(2*d2+1)*64 + 2*e2];
        *(unsigned int*)&dst[(2*e2)*64 + 2*d2]   = pack2h(a0.x, a1.x);
        *(unsigned int*)&dst[(2*e2+1)*64 + 2*d2] = pack2h(a0.y, a1.y);
    }
}

extern "C" void kernel_launch(void* const* d_in, const int* in_sizes, int n_in,
                              void* d_out, int out_size, void* d_ws, size_t ws_size,
                              hipStream_t stream)
{
    (void)in_sizes; (void)n_in; (void)out_size; (void)ws_size;
    const float* x  = (const float*)d_in[0];
    const float* y  = (const float*)d_in[1];
    const float* Wq = (const float*)d_in[2];
    const float* bq = (const float*)d_in[3];
    const float* Wk = (const float*)d_in[4];
    const float* bk = (const float*)d_in[5];
    const float* lw = (const float*)d_in[6];
    const float* lb = (const float*)d_in[7];

    char* ws = (char*)d_ws;
    float*    cosT = (float*)(ws + OFF_COS);
    float*    sinT = (float*)(ws + OFF_SIN);
    _Float16* krh  = (_Float16*)(ws + OFF_KRH);   // then reused as xh
    _Float16* yh   = (_Float16*)(ws + OFF_YH);
    _Float16* Wqh  = (_Float16*)(ws + OFF_WQH);
    _Float16* Wkh  = (_Float16*)(ws + OFF_WKH);
    float*    ksum = (float*)(ws + OFF_KSUM);
    float*    kvg  = (float*)(ws + OFF_KVG);
    _Float16* kvTg = (_Float16*)(ws + OFF_KVT);
    float*    out  = (float*)d_out;

    hipMemsetAsync(ws + OFF_KSUM, 0, 64*1024 + 1024*1024, stream);
    k_tables<<<dim3(N_), dim3(256), 0, stream>>>(cosT, sinT);
    k_prep_y<<<dim3(8448), dim3(256), 0, stream>>>(y, Wq, Wk, yh, Wqh, Wkh);
    k_gemm<0><<<dim3(4, 256), dim3(256), 0, stream>>>(yh, Wkh, bk, cosT, sinT,
        krh, ksum, nullptr, nullptr, nullptr, nullptr, nullptr, nullptr);
    k_kv<<<dim3(8, 64), dim3(256), 0, stream>>>(krh, yh, kvg);
    k_kvmerge<<<dim3(64), dim3(256), 0, stream>>>(kvg, kvTg);
    k_prep_x<<<dim3(8192), dim3(256), 0, stream>>>(x, krh);   // xh overwrites retired krh
    k_gemm<1><<<dim3(4, 256), dim3(256), 0, stream>>>(krh, Wqh, bq, cosT, sinT,
        nullptr, nullptr, ksum, kvTg, yh, lw, lb, out);
}

// Round 7
// 200.528 us; speedup vs baseline: 1.0709x; 1.0505x over previous
//
#include <hip/hip_runtime.h>

#define B_ 8
#define N_ 4096
#define C_ 512
#define H_ 8

typedef _Float16 h8  __attribute__((ext_vector_type(8)));
typedef _Float16 h4v __attribute__((ext_vector_type(4)));
typedef float    f4  __attribute__((ext_vector_type(4)));

// ---- workspace layout (bytes), peak ~74.6 MiB ----
static const size_t OFF_COS  = 0;                                  // 4 MiB f32 [4096][256]
static const size_t OFF_SIN  = (size_t)4*1024*1024;                // 4 MiB
static const size_t OFF_KRH  = (size_t)8*1024*1024;                // 32 MiB f16 [B*N][C]: krh, later reused as xh
static const size_t OFF_YH   = (size_t)40*1024*1024;               // 32 MiB f16 [B*N][C]
static const size_t OFF_WQH  = (size_t)72*1024*1024;               // 512 KiB f16
static const size_t OFF_WKH  = (size_t)72*1024*1024 + 512*1024;    // 512 KiB f16
static const size_t OFF_KSUM = (size_t)73*1024*1024;               // 16 KiB f32 (64K slot)
static const size_t OFF_KVG  = (size_t)73*1024*1024 + 64*1024;     // 1 MiB f32 [64bh][64d][64e]
static const size_t OFF_KVT  = (size_t)74*1024*1024 + 64*1024;     // 512 KiB f16 [64bh][64e][64d]

__device__ __forceinline__ unsigned int pack2h(float a, float b){
    union { _Float16 h[2]; unsigned int u; } x;
    x.h[0] = (_Float16)a; x.h[1] = (_Float16)b; return x.u;
}

// ---- cos/sin tables ----
__global__ void k_tables(float* __restrict__ cosT, float* __restrict__ sinT){
    int n = blockIdx.x, j = threadIdx.x;
    double th = exp((double)j * -0.035977892078031970); // ln(1e4)/256
    float ang = (float)n * (float)th;
    float s, c; sincosf(ang, &s, &c);
    cosT[n*256 + j] = c; sinT[n*256 + j] = s;
}

// ---- f32 -> f16 streaming converts: y + Wq + Wk ----
__global__ __launch_bounds__(256) void k_prep_y(
    const float* __restrict__ y, const float* __restrict__ Wq, const float* __restrict__ Wk,
    _Float16* __restrict__ yh, _Float16* __restrict__ Wqh, _Float16* __restrict__ Wkh)
{
    int bid = blockIdx.x;
    const float* src; _Float16* dst; size_t base;
    if (bid < 8192)      { src = y;  dst = yh;  base = (size_t)bid*2048; }
    else if (bid < 8320) { src = Wq; dst = Wqh; base = (size_t)(bid-8192)*2048; }
    else                 { src = Wk; dst = Wkh; base = (size_t)(bid-8320)*2048; }
    size_t o = base + (size_t)threadIdx.x*8;
    float4 a = *(const float4*)&src[o];
    float4 b = *(const float4*)&src[o+4];
    uint4 r; r.x = pack2h(a.x,a.y); r.y = pack2h(a.z,a.w); r.z = pack2h(b.x,b.y); r.w = pack2h(b.z,b.w);
    *(uint4*)&dst[o] = r;
}

// ---- x -> f16 (into the retired krh region) ----
__global__ __launch_bounds__(256) void k_prep_x(const float* __restrict__ x, _Float16* __restrict__ xh){
    size_t o = (size_t)blockIdx.x*2048 + (size_t)threadIdx.x*8;
    float4 a = *(const float4*)&x[o];
    float4 b = *(const float4*)&x[o+4];
    uint4 r; r.x = pack2h(a.x,a.y); r.y = pack2h(a.z,a.w); r.z = pack2h(b.x,b.y); r.w = pack2h(b.z,b.w);
    *(uint4*)&xh[o] = r;
}

// ---- stage f16 tiles via global_load_lds; linear dest, source pre-swizzled ----
// phys 16B-unit p = r*4 + (j ^ s(r)), s(r) = (r ^ (r>>2)) & 3
__device__ __forceinline__ void stage_a64(const _Float16* __restrict__ g, _Float16* lds, int t){
    int r = t >> 2;
    int j = (t & 3) ^ ((r ^ (r >> 2)) & 3);
    __builtin_amdgcn_global_load_lds(
        (const __attribute__((address_space(1))) void*)(g + (size_t)r*C_ + j*8),
        (__attribute__((address_space(3))) void*)(lds + (size_t)(t & 192)*8),
        16, 0, 0);
}
__device__ __forceinline__ void stage_b128(const _Float16* __restrict__ g, _Float16* lds, int t){
#pragma unroll
    for (int i=0;i<2;++i){
        int u = i*256 + t;
        int r = u >> 2;
        int j = (u & 3) ^ ((r ^ (r >> 2)) & 3);
        __builtin_amdgcn_global_load_lds(
            (const __attribute__((address_space(1))) void*)(g + (size_t)r*C_ + j*8),
            (__attribute__((address_space(3))) void*)(lds + (size_t)(i*256 + (t & 192))*8),
            16, 0, 0);
    }
}

// ---- fused GEMM, BM=64 x BN=128, m97-shape loop; grid (4, 512) ----
// IS_Q=0: k path (-> krh, ksum); IS_Q=1: q path (fused z, qr@kv from L2-regs, lepe, coalesced out)
template<int IS_Q>
__global__ __launch_bounds__(256, 5) void k_gemm(
    const _Float16* __restrict__ A, const _Float16* __restrict__ Wh, const float* __restrict__ bias,
    const float* __restrict__ cosT, const float* __restrict__ sinT,
    _Float16* __restrict__ krh, float* __restrict__ ksum,
    const float* __restrict__ ksumIn, const _Float16* __restrict__ kvTg,
    const _Float16* __restrict__ yh, const float* __restrict__ lw, const float* __restrict__ lb,
    float* __restrict__ outp)
{
    // main: As@0 (2x4096), Bs@8192 (2x8192) = 24576. epilogue: qrs@0 = 4 waves x [32][72] = 18432
    __shared__ __align__(16) char smem[24576];
    _Float16* qrs = (_Float16*)smem;

    const int t = threadIdx.x;
    const int lane = t & 63;
    const int w = t >> 6;
    const int wm = w >> 1, wn = w & 1;
    const int col0 = blockIdx.x * 128;
    const int row0 = blockIdx.y * 64;
    const int lrow = lane & 15, lg = lane >> 4;
    const int b = row0 >> 12;

    f4 acc[2][4] = {};
    stage_a64(A  + (size_t)row0*C_, (_Float16*)smem, t);
    stage_b128(Wh + (size_t)col0*C_, (_Float16*)(smem + 8192), t);

    const int sw = (lrow ^ (lrow >> 2)) & 3;
    const int cK = (lg ^ sw) * 8;
    int cur = 0;

    for (int kk=0; kk<16; ++kk){
        __syncthreads();   // staged tile [cur] ready
        if (kk < 15){
            stage_a64(A  + (size_t)row0*C_ + (kk+1)*32, (_Float16*)(smem + (cur^1)*4096), t);
            stage_b128(Wh + (size_t)col0*C_ + (kk+1)*32, (_Float16*)(smem + 8192 + (cur^1)*8192), t);
        }
        const _Float16* As = (const _Float16*)(smem + cur*4096);
        const _Float16* Bs = (const _Float16*)(smem + 8192 + cur*8192);
        h8 af[2], bf[4];
#pragma unroll
        for (int mi=0; mi<2; ++mi) af[mi] = *(const h8*)&As[(wm*32 + mi*16 + lrow)*32 + cK];
#pragma unroll
        for (int ni=0; ni<4; ++ni) bf[ni] = *(const h8*)&Bs[(wn*64 + ni*16 + lrow)*32 + cK];
#pragma unroll
        for (int mi=0; mi<2; ++mi)
#pragma unroll
            for (int ni=0; ni<4; ++ni)
                acc[mi][ni] = __builtin_amdgcn_mfma_f32_16x16x32_f16(af[mi], bf[ni], acc[mi][ni], 0,0,0);
        __syncthreads();   // reads of [cur] done before overwrite
        cur ^= 1;
    }

    // ---- epilogue ----
    const int hcol0 = col0 + wn*64;
    float bcol[4], km[4];
#pragma unroll
    for (int ni=0; ni<4; ++ni){
        int c = hcol0 + ni*16 + lrow;
        bcol[ni] = bias[c];
        km[ni] = IS_Q ? ksumIn[b*C_ + c] * (1.0f/4096.0f) : 0.0f;
    }
    float colsum[4] = {0.f,0.f,0.f,0.f};
    float zr[2][4];
    _Float16* qw = qrs + w*2304;   // wave-local [32][72]

#pragma unroll
    for (int mi=0; mi<2; ++mi){
        float qv[4][4];
#pragma unroll
        for (int ni=0; ni<4; ++ni)
#pragma unroll
            for (int r=0; r<4; ++r){
                float v = acc[mi][ni][r] + bcol[ni];
                qv[ni][r] = v > 0.f ? v + 1.f : __expf(v);   // elu+1
            }
        if constexpr (IS_Q){
#pragma unroll
            for (int r=0; r<4; ++r){
                float p = qv[0][r]*km[0] + qv[1][r]*km[1] + qv[2][r]*km[2] + qv[3][r]*km[3];
                p += __shfl_xor(p, 1); p += __shfl_xor(p, 2);
                p += __shfl_xor(p, 4); p += __shfl_xor(p, 8);
                zr[mi][r] = 1.0f / (p + 1e-6f);
            }
        } else {
#pragma unroll
            for (int ni=0; ni<4; ++ni)
                colsum[ni] += qv[ni][0]+qv[ni][1]+qv[ni][2]+qv[ni][3];
        }
        // rope
#pragma unroll
        for (int ni=0; ni<4; ++ni){
            int c = hcol0 + ni*16 + lrow;
            int jj = c >> 1;
#pragma unroll
            for (int r=0; r<4; ++r){
                int grow = row0 + wm*32 + mi*16 + lg*4 + r;
                int n = grow & (N_-1);
                float val = qv[ni][r];
                float par = __shfl_xor(val, 1);
                float cs = cosT[n*256 + jj], sn = sinT[n*256 + jj];
                float rv = (lane & 1) ? fmaf(sn, par, cs*val) : fmaf(cs, val, -sn*par);
                float prv = __shfl_xor(rv, 1);
                if constexpr (IS_Q){
                    if (!(lane & 1))
                        *(unsigned int*)&qw[(mi*16 + lg*4 + r)*72 + (ni*16 + lrow)] = pack2h(rv, prv);
                } else {
                    if (!(lane & 1))
                        *(unsigned int*)&krh[(size_t)grow*C_ + c] = pack2h(rv, prv);
                }
            }
        }
    }

    if constexpr (!IS_Q){
#pragma unroll
        for (int ni=0; ni<4; ++ni){
            float s = colsum[ni];
            s += __shfl_xor(s, 16); s += __shfl_xor(s, 32);
            if (lane < 16) atomicAdd(&ksum[b*C_ + hcol0 + ni*16 + lane], s);
        }
    } else {
        // kv fragments straight from L2 (kvTg is 512 KiB, resident)
        const int bhh = b*H_ + (col0 >> 6) + wn;
        h8 kv0[4], kv1[4];
#pragma unroll
        for (int ni2=0; ni2<4; ++ni2){
            int e = ni2*16 + lrow;
            kv0[ni2] = *(const h8*)&kvTg[(size_t)bhh*4096 + e*64 + lg*8];
            kv1[ni2] = *(const h8*)&kvTg[(size_t)bhh*4096 + e*64 + 32 + lg*8];
        }
        __syncthreads();   // qrs written by all waves
        // wave-local out-gemm: out[32n x 64e] = qr(32x64) @ kv(64x64)
        f4 acc2[2][4] = {};
#pragma unroll
        for (int mi2=0; mi2<2; ++mi2){
            h8 a0 = *(const h8*)&qw[(mi2*16 + lrow)*72 + 0*32 + lg*8];
            h8 a1 = *(const h8*)&qw[(mi2*16 + lrow)*72 + 1*32 + lg*8];
#pragma unroll
            for (int ni2=0; ni2<4; ++ni2){
                acc2[mi2][ni2] = __builtin_amdgcn_mfma_f32_16x16x32_f16(a0, kv0[ni2], acc2[mi2][ni2], 0,0,0);
                acc2[mi2][ni2] = __builtin_amdgcn_mfma_f32_16x16x32_f16(a1, kv1[ni2], acc2[mi2][ni2], 0,0,0);
            }
        }
        // z-scale, write back f16 into own qw tile
#pragma unroll
        for (int mi2=0; mi2<2; ++mi2){
#pragma unroll
            for (int r=0; r<4; ++r){
                float z = zr[mi2][r];
#pragma unroll
                for (int ni2=0; ni2<4; ++ni2){
                    float val = acc2[mi2][ni2][r] * z;
                    float pv = __shfl_xor(val, 1);
                    if (!(lane & 1))
                        *(unsigned int*)&qw[(mi2*16 + lg*4 + r)*72 + (ni2*16 + lrow)] = pack2h(val, pv);
                }
            }
        }
        __syncthreads();
        // row-major remap: lepe (reads yh) + out, fully coalesced
        const int cg = t & 31;
        const int c4p = cg * 4;
        const int hl = c4p >> 6;
        const int e0 = c4p & 63;
        float w0[4], w1[4], w2[4], wb[4];
#pragma unroll
        for (int j=0;j<4;++j){
            int cc = col0 + c4p + j;
            w0[j]=lw[cc*3+0]; w1[j]=lw[cc*3+1]; w2[j]=lw[cc*3+2]; wb[j]=lb[cc];
        }
#pragma unroll
        for (int i=0;i<8;++i){
            int rl = (t >> 5) + i*8;
            int grow = row0 + rl;
            int nloc = grow & (N_-1);
            int wreg = ((rl >> 5) << 1) + hl;
            h4v a = *(const h4v*)&qrs[wreg*2304 + (rl & 31)*72 + e0];
            const _Float16* yp = yh + (size_t)grow*C_ + col0 + c4p;
            h4v y1 = *(const h4v*)yp;
            float s0 = fmaf((float)y1[0], w1[0], wb[0]);
            float s1 = fmaf((float)y1[1], w1[1], wb[1]);
            float s2 = fmaf((float)y1[2], w1[2], wb[2]);
            float s3 = fmaf((float)y1[3], w1[3], wb[3]);
            if (nloc > 0){
                h4v y0 = *(const h4v*)(yp - C_);
                s0 = fmaf((float)y0[0], w0[0], s0); s1 = fmaf((float)y0[1], w0[1], s1);
                s2 = fmaf((float)y0[2], w0[2], s2); s3 = fmaf((float)y0[3], w0[3], s3);
            }
            if (nloc < N_-1){
                h4v y2 = *(const h4v*)(yp + C_);
                s0 = fmaf((float)y2[0], w2[0], s0); s1 = fmaf((float)y2[1], w2[1], s1);
                s2 = fmaf((float)y2[2], w2[2], s2); s3 = fmaf((float)y2[3], w2[3], s3);
            }
            float4 o;
            o.x = (float)a[0] + s0; o.y = (float)a[1] + s1;
            o.z = (float)a[2] + s2; o.w = (float)a[3] + s3;
            *(float4*)&outp[(size_t)grow*C_ + col0 + c4p] = o;
        }
    }
}

// ---- kv = (1/N) k_rope^T @ v : both operands f16, LDS-transposed, chunk-XOR swizzle ----
__global__ __launch_bounds__(256) void k_kv(const _Float16* __restrict__ krh, const _Float16* __restrict__ yh,
                                            float* __restrict__ kvg){
    __shared__ _Float16 krs[64*128];
    __shared__ _Float16 vs[64*128];
    const int split = blockIdx.x, bh = blockIdx.y;
    const int b = bh >> 3, h = bh & 7;
    const int t = threadIdx.x, lane = t & 63, w = t >> 6;
    const int lrow = lane & 15, lg = lane >> 4;
    f4 acc[4] = {};
    for (int sub=0; sub<4; ++sub){
        const int n0 = split*512 + sub*128;
#pragma unroll
        for (int i=0;i<8;++i){
            int q = i*256 + t;
            int d2 = q & 31, n2 = q >> 5;
            int n = n0 + 2*n2, c = h*64 + 2*d2;
            size_t g0 = (size_t)(b*N_ + n)*C_ + c;
            unsigned int u0 = *(const unsigned int*)&krh[g0];
            unsigned int u1 = *(const unsigned int*)&krh[g0 + C_];
            unsigned int v0 = *(const unsigned int*)&yh[g0];
            unsigned int v1 = *(const unsigned int*)&yh[g0 + C_];
            int chunk = n2 >> 2, j2 = (n2 & 3)*2;
            int pc0 = chunk ^ ((2*d2) & 15);
            int pc1 = pc0 ^ 1;
            *(unsigned int*)&krs[(2*d2)*128 + pc0*8 + j2]   = (u0 & 0xffffu) | (u1 << 16);
            *(unsigned int*)&krs[(2*d2+1)*128 + pc1*8 + j2] = (u0 >> 16) | (u1 & 0xffff0000u);
            *(unsigned int*)&vs[(2*d2)*128 + pc0*8 + j2]    = (v0 & 0xffffu) | (v1 << 16);
            *(unsigned int*)&vs[(2*d2+1)*128 + pc1*8 + j2]  = (v0 >> 16) | (v1 & 0xffff0000u);
        }
        __syncthreads();
#pragma unroll
        for (int ks=0; ks<4; ++ks){
            int cu = ((ks*4 + lg) ^ lrow)*8;
            h8 a = *(const h8*)&krs[(w*16 + lrow)*128 + cu];
#pragma unroll
            for (int ni=0; ni<4; ++ni){
                h8 bv = *(const h8*)&vs[(ni*16 + lrow)*128 + cu];
                acc[ni] = __builtin_amdgcn_mfma_f32_16x16x32_f16(a, bv, acc[ni], 0,0,0);
            }
        }
        __syncthreads();
    }
#pragma unroll
    for (int ni=0; ni<4; ++ni)
#pragma unroll
        for (int rr=0; rr<4; ++rr)
            atomicAdd(&kvg[(size_t)bh*4096 + (w*16 + lg*4 + rr)*64 + ni*16 + lrow],
                      acc[ni][rr] * (1.0f/4096.0f));
}

// ---- kvg f32 [bh][d][e] -> kvTg f16 [bh][e][d] ----
__global__ __launch_bounds__(256) void k_kvmerge(const float* __restrict__ kvg, _Float16* __restrict__ kvTg){
    int bh = blockIdx.x, t = threadIdx.x;
    const float* src = kvg + (size_t)bh*4096;
    _Float16* dst = kvTg + (size_t)bh*4096;
#pragma unroll
    for (int i=0;i<4;++i){
        int q = i*256 + t;
        int e2 = q & 31, d2 = q >> 5;
        float2 a0 = *(const float2*)&src[(2*d2)*64 + 2*e2];
        float2 a1 = *(const float2*)&src[(2*d2+1)*64 + 2*e2];
        *(unsigned int*)&dst[(2*e2)*64 + 2*d2]   = pack2h(a0.x, a1.x);
        *(unsigned int*)&dst[(2*e2+1)*64 + 2*d2] = pack2h(a0.y, a1.y);
    }
}

extern "C" void kernel_launch(void* const* d_in, const int* in_sizes, int n_in,
                              void* d_out, int out_size, void* d_ws, size_t ws_size,
                              hipStream_t stream)
{
    (void)in_sizes; (void)n_in; (void)out_size; (void)ws_size;
    const float* x  = (const float*)d_in[0];
    const float* y  = (const float*)d_in[1];
    const float* Wq = (const float*)d_in[2];
    const float* bq = (const float*)d_in[3];
    const float* Wk = (const float*)d_in[4];
    const float* bk = (const float*)d_in[5];
    const float* lw = (const float*)d_in[6];
    const float* lb = (const float*)d_in[7];

    char* ws = (char*)d_ws;
    float*    cosT = (float*)(ws + OFF_COS);
    float*    sinT = (float*)(ws + OFF_SIN);
    _Float16* krh  = (_Float16*)(ws + OFF_KRH);   // then reused as xh
    _Float16* yh   = (_Float16*)(ws + OFF_YH);
    _Float16* Wqh  = (_Float16*)(ws + OFF_WQH);
    _Float16* Wkh  = (_Float16*)(ws + OFF_WKH);
    float*    ksum = (float*)(ws + OFF_KSUM);
    float*    kvg  = (float*)(ws + OFF_KVG);
    _Float16* kvTg = (_Float16*)(ws + OFF_KVT);
    float*    out  = (float*)d_out;

    hipMemsetAsync(ws + OFF_KSUM, 0, 64*1024 + 1024*1024, stream);
    k_tables<<<dim3(N_), dim3(256), 0, stream>>>(cosT, sinT);
    k_prep_y<<<dim3(8448), dim3(256), 0, stream>>>(y, Wq, Wk, yh, Wqh, Wkh);
    k_gemm<0><<<dim3(4, 512), dim3(256), 0, stream>>>(yh, Wkh, bk, cosT, sinT,
        krh, ksum, nullptr, nullptr, nullptr, nullptr, nullptr, nullptr);
    k_kv<<<dim3(8, 64), dim3(256), 0, stream>>>(krh, yh, kvg);
    k_kvmerge<<<dim3(64), dim3(256), 0, stream>>>(kvg, kvTg);
    k_prep_x<<<dim3(8192), dim3(256), 0, stream>>>(x, krh);   // xh overwrites retired krh
    k_gemm<1><<<dim3(4, 512), dim3(256), 0, stream>>>(krh, Wqh, bq, cosT, sinT,
        nullptr, nullptr, ksum, kvTg, yh, lw, lb, out);
}

// Round 8
// 195.583 us; speedup vs baseline: 1.0980x; 1.0253x over previous
//
#include <hip/hip_runtime.h>

#define B_ 8
#define N_ 4096
#define C_ 512
#define H_ 8

typedef _Float16 h8  __attribute__((ext_vector_type(8)));
typedef _Float16 h4v __attribute__((ext_vector_type(4)));
typedef float    f4  __attribute__((ext_vector_type(4)));

// ---- workspace layout (bytes), peak ~74.6 MiB ----
static const size_t OFF_COS  = 0;                                  // 4 MiB f32 [4096][256]
static const size_t OFF_SIN  = (size_t)4*1024*1024;                // 4 MiB
static const size_t OFF_KRH  = (size_t)8*1024*1024;                // 32 MiB f16 [B*N][C]: krh, later reused as xh
static const size_t OFF_YH   = (size_t)40*1024*1024;               // 32 MiB f16 [B*N][C]
static const size_t OFF_WQH  = (size_t)72*1024*1024;               // 512 KiB f16
static const size_t OFF_WKH  = (size_t)72*1024*1024 + 512*1024;    // 512 KiB f16
static const size_t OFF_KSUM = (size_t)73*1024*1024;               // 16 KiB f32 (64K slot)
static const size_t OFF_KVG  = (size_t)73*1024*1024 + 64*1024;     // 1 MiB f32 [64bh][64d][64e]
static const size_t OFF_KVT  = (size_t)74*1024*1024 + 64*1024;     // 512 KiB f16 [64bh][64e][64d]

__device__ __forceinline__ unsigned int pack2h(float a, float b){
    union { _Float16 h[2]; unsigned int u; } x;
    x.h[0] = (_Float16)a; x.h[1] = (_Float16)b; return x.u;
}

// ---- cos/sin tables ----
__global__ void k_tables(float* __restrict__ cosT, float* __restrict__ sinT){
    int n = blockIdx.x, j = threadIdx.x;
    double th = exp((double)j * -0.035977892078031970); // ln(1e4)/256
    float ang = (float)n * (float)th;
    float s, c; sincosf(ang, &s, &c);
    cosT[n*256 + j] = c; sinT[n*256 + j] = s;
}

// ---- f32 -> f16 streaming converts: y + Wq + Wk ----
__global__ __launch_bounds__(256) void k_prep_y(
    const float* __restrict__ y, const float* __restrict__ Wq, const float* __restrict__ Wk,
    _Float16* __restrict__ yh, _Float16* __restrict__ Wqh, _Float16* __restrict__ Wkh)
{
    int bid = blockIdx.x;
    const float* src; _Float16* dst; size_t base;
    if (bid < 8192)      { src = y;  dst = yh;  base = (size_t)bid*2048; }
    else if (bid < 8320) { src = Wq; dst = Wqh; base = (size_t)(bid-8192)*2048; }
    else                 { src = Wk; dst = Wkh; base = (size_t)(bid-8320)*2048; }
    size_t o = base + (size_t)threadIdx.x*8;
    float4 a = *(const float4*)&src[o];
    float4 b = *(const float4*)&src[o+4];
    uint4 r; r.x = pack2h(a.x,a.y); r.y = pack2h(a.z,a.w); r.z = pack2h(b.x,b.y); r.w = pack2h(b.z,b.w);
    *(uint4*)&dst[o] = r;
}

// ---- x -> f16 (into the retired krh region) ----
__global__ __launch_bounds__(256) void k_prep_x(const float* __restrict__ x, _Float16* __restrict__ xh){
    size_t o = (size_t)blockIdx.x*2048 + (size_t)threadIdx.x*8;
    float4 a = *(const float4*)&x[o];
    float4 b = *(const float4*)&x[o+4];
    uint4 r; r.x = pack2h(a.x,a.y); r.y = pack2h(a.z,a.w); r.z = pack2h(b.x,b.y); r.w = pack2h(b.z,b.w);
    *(uint4*)&xh[o] = r;
}

// ---- stage f16 tiles via global_load_lds; linear dest, source pre-swizzled ----
// phys 16B-unit p = r*4 + (j ^ s(r)), s(r) = (r ^ (r>>2)) & 3
__device__ __forceinline__ void stage_a64(const _Float16* __restrict__ g, _Float16* lds, int t){
    int r = t >> 2;
    int j = (t & 3) ^ ((r ^ (r >> 2)) & 3);
    __builtin_amdgcn_global_load_lds(
        (const __attribute__((address_space(1))) void*)(g + (size_t)r*C_ + j*8),
        (__attribute__((address_space(3))) void*)(lds + (size_t)(t & 192)*8),
        16, 0, 0);
}
__device__ __forceinline__ void stage_b128(const _Float16* __restrict__ g, _Float16* lds, int t){
#pragma unroll
    for (int i=0;i<2;++i){
        int u = i*256 + t;
        int r = u >> 2;
        int j = (u & 3) ^ ((r ^ (r >> 2)) & 3);
        __builtin_amdgcn_global_load_lds(
            (const __attribute__((address_space(1))) void*)(g + (size_t)r*C_ + j*8),
            (__attribute__((address_space(3))) void*)(lds + (size_t)(i*256 + (t & 192))*8),
            16, 0, 0);
    }
}

// ---- fused GEMM, BM=64 x BN=128; triple-buffered, counted-vmcnt pipeline; grid (4, 512) ----
// vmcnt discipline: 3 loads/stage (A:1 + B:2); depth-2 prefetch -> wait vmcnt(3) (never 0 in loop).
// IS_Q=0: k path (-> krh, ksum); IS_Q=1: q path (fused z, qr@kv from L2-regs, lepe, coalesced out)
template<int IS_Q>
__global__ __launch_bounds__(256, 4) void k_gemm(
    const _Float16* __restrict__ A, const _Float16* __restrict__ Wh, const float* __restrict__ bias,
    const float* __restrict__ cosT, const float* __restrict__ sinT,
    _Float16* __restrict__ krh, float* __restrict__ ksum,
    const float* __restrict__ ksumIn, const _Float16* __restrict__ kvTg,
    const _Float16* __restrict__ yh, const float* __restrict__ lw, const float* __restrict__ lb,
    float* __restrict__ outp)
{
    // main: A slots 3x4096 @0, B slots 3x8192 @12288 = 36864. epilogue: qrs@0 = 4 x [32][72] = 18432
    __shared__ __align__(16) char smem[36864];
    _Float16* qrs = (_Float16*)smem;

    const int t = threadIdx.x;
    const int lane = t & 63;
    const int w = t >> 6;
    const int wm = w >> 1, wn = w & 1;
    const int col0 = blockIdx.x * 128;
    const int row0 = blockIdx.y * 64;
    const int lrow = lane & 15, lg = lane >> 4;
    const int b = row0 >> 12;

    f4 acc[2][4] = {};
    const _Float16* Ab = A  + (size_t)row0*C_;
    const _Float16* Bb = Wh + (size_t)col0*C_;
    // prologue: tiles 0 and 1 in flight (6 loads)
    stage_a64 (Ab,      (_Float16*)(smem),               t);
    stage_b128(Bb,      (_Float16*)(smem + 12288),       t);
    stage_a64 (Ab + 32, (_Float16*)(smem + 4096),        t);
    stage_b128(Bb + 32, (_Float16*)(smem + 12288 + 8192),t);

    const int sw = (lrow ^ (lrow >> 2)) & 3;
    const int cK = (lg ^ sw) * 8;

#pragma unroll
    for (int kk=0; kk<16; ++kk){
        if (kk < 15) asm volatile("s_waitcnt vmcnt(3)" ::: "memory");
        else         asm volatile("s_waitcnt vmcnt(0)" ::: "memory");
        __builtin_amdgcn_s_barrier();
        if (kk < 14){
            const int ss = (kk+2)%3;
            stage_a64 (Ab + (kk+2)*32, (_Float16*)(smem + ss*4096),         t);
            stage_b128(Bb + (kk+2)*32, (_Float16*)(smem + 12288 + ss*8192), t);
        }
        const int sc = kk%3;
        const _Float16* As = (const _Float16*)(smem + sc*4096);
        const _Float16* Bs = (const _Float16*)(smem + 12288 + sc*8192);
        h8 af[2], bf[4];
#pragma unroll
        for (int mi=0; mi<2; ++mi) af[mi] = *(const h8*)&As[(wm*32 + mi*16 + lrow)*32 + cK];
#pragma unroll
        for (int ni=0; ni<4; ++ni) bf[ni] = *(const h8*)&Bs[(wn*64 + ni*16 + lrow)*32 + cK];
#pragma unroll
        for (int mi=0; mi<2; ++mi)
#pragma unroll
            for (int ni=0; ni<4; ++ni)
                acc[mi][ni] = __builtin_amdgcn_mfma_f32_16x16x32_f16(af[mi], bf[ni], acc[mi][ni], 0,0,0);
    }
    __syncthreads();   // all LDS reads done; slots reusable as qrs

    // ---- epilogue ----
    const int hcol0 = col0 + wn*64;
    float bcol[4], km[4];
#pragma unroll
    for (int ni=0; ni<4; ++ni){
        int c = hcol0 + ni*16 + lrow;
        bcol[ni] = bias[c];
        km[ni] = IS_Q ? ksumIn[b*C_ + c] * (1.0f/4096.0f) : 0.0f;
    }
    float colsum[4] = {0.f,0.f,0.f,0.f};
    float zr[2][4];
    _Float16* qw = qrs + w*2304;   // wave-local [32][72]

#pragma unroll
    for (int mi=0; mi<2; ++mi){
        float qv[4][4];
#pragma unroll
        for (int ni=0; ni<4; ++ni)
#pragma unroll
            for (int r=0; r<4; ++r){
                float v = acc[mi][ni][r] + bcol[ni];
                qv[ni][r] = v > 0.f ? v + 1.f : __expf(v);   // elu+1
            }
        if constexpr (IS_Q){
#pragma unroll
            for (int r=0; r<4; ++r){
                float p = qv[0][r]*km[0] + qv[1][r]*km[1] + qv[2][r]*km[2] + qv[3][r]*km[3];
                p += __shfl_xor(p, 1); p += __shfl_xor(p, 2);
                p += __shfl_xor(p, 4); p += __shfl_xor(p, 8);
                zr[mi][r] = 1.0f / (p + 1e-6f);
            }
        } else {
#pragma unroll
            for (int ni=0; ni<4; ++ni)
                colsum[ni] += qv[ni][0]+qv[ni][1]+qv[ni][2]+qv[ni][3];
        }
        // rope
#pragma unroll
        for (int ni=0; ni<4; ++ni){
            int c = hcol0 + ni*16 + lrow;
            int jj = c >> 1;
#pragma unroll
            for (int r=0; r<4; ++r){
                int grow = row0 + wm*32 + mi*16 + lg*4 + r;
                int n = grow & (N_-1);
                float val = qv[ni][r];
                float par = __shfl_xor(val, 1);
                float cs = cosT[n*256 + jj], sn = sinT[n*256 + jj];
                float rv = (lane & 1) ? fmaf(sn, par, cs*val) : fmaf(cs, val, -sn*par);
                float prv = __shfl_xor(rv, 1);
                if constexpr (IS_Q){
                    if (!(lane & 1))
                        *(unsigned int*)&qw[(mi*16 + lg*4 + r)*72 + (ni*16 + lrow)] = pack2h(rv, prv);
                } else {
                    if (!(lane & 1))
                        *(unsigned int*)&krh[(size_t)grow*C_ + c] = pack2h(rv, prv);
                }
            }
        }
    }

    if constexpr (!IS_Q){
#pragma unroll
        for (int ni=0; ni<4; ++ni){
            float s = colsum[ni];
            s += __shfl_xor(s, 16); s += __shfl_xor(s, 32);
            if (lane < 16) atomicAdd(&ksum[b*C_ + hcol0 + ni*16 + lane], s);
        }
    } else {
        // kv fragments straight from L2 (kvTg is 512 KiB, resident)
        const int bhh = b*H_ + (col0 >> 6) + wn;
        h8 kv0[4], kv1[4];
#pragma unroll
        for (int ni2=0; ni2<4; ++ni2){
            int e = ni2*16 + lrow;
            kv0[ni2] = *(const h8*)&kvTg[(size_t)bhh*4096 + e*64 + lg*8];
            kv1[ni2] = *(const h8*)&kvTg[(size_t)bhh*4096 + e*64 + 32 + lg*8];
        }
        __syncthreads();   // qrs written by all waves
        // wave-local out-gemm: out[32n x 64e] = qr(32x64) @ kv(64x64)
        f4 acc2[2][4] = {};
#pragma unroll
        for (int mi2=0; mi2<2; ++mi2){
            h8 a0 = *(const h8*)&qw[(mi2*16 + lrow)*72 + 0*32 + lg*8];
            h8 a1 = *(const h8*)&qw[(mi2*16 + lrow)*72 + 1*32 + lg*8];
#pragma unroll
            for (int ni2=0; ni2<4; ++ni2){
                acc2[mi2][ni2] = __builtin_amdgcn_mfma_f32_16x16x32_f16(a0, kv0[ni2], acc2[mi2][ni2], 0,0,0);
                acc2[mi2][ni2] = __builtin_amdgcn_mfma_f32_16x16x32_f16(a1, kv1[ni2], acc2[mi2][ni2], 0,0,0);
            }
        }
        // z-scale, write back f16 into own qw tile
#pragma unroll
        for (int mi2=0; mi2<2; ++mi2){
#pragma unroll
            for (int r=0; r<4; ++r){
                float z = zr[mi2][r];
#pragma unroll
                for (int ni2=0; ni2<4; ++ni2){
                    float val = acc2[mi2][ni2][r] * z;
                    float pv = __shfl_xor(val, 1);
                    if (!(lane & 1))
                        *(unsigned int*)&qw[(mi2*16 + lg*4 + r)*72 + (ni2*16 + lrow)] = pack2h(val, pv);
                }
            }
        }
        __syncthreads();
        // row-major remap: lepe (reads yh) + out, fully coalesced
        const int cg = t & 31;
        const int c4p = cg * 4;
        const int hl = c4p >> 6;
        const int e0 = c4p & 63;
        float w0[4], w1[4], w2[4], wb[4];
#pragma unroll
        for (int j=0;j<4;++j){
            int cc = col0 + c4p + j;
            w0[j]=lw[cc*3+0]; w1[j]=lw[cc*3+1]; w2[j]=lw[cc*3+2]; wb[j]=lb[cc];
        }
#pragma unroll
        for (int i=0;i<8;++i){
            int rl = (t >> 5) + i*8;
            int grow = row0 + rl;
            int nloc = grow & (N_-1);
            int wreg = ((rl >> 5) << 1) + hl;
            h4v a = *(const h4v*)&qrs[wreg*2304 + (rl & 31)*72 + e0];
            const _Float16* yp = yh + (size_t)grow*C_ + col0 + c4p;
            h4v y1 = *(const h4v*)yp;
            float s0 = fmaf((float)y1[0], w1[0], wb[0]);
            float s1 = fmaf((float)y1[1], w1[1], wb[1]);
            float s2 = fmaf((float)y1[2], w1[2], wb[2]);
            float s3 = fmaf((float)y1[3], w1[3], wb[3]);
            if (nloc > 0){
                h4v y0 = *(const h4v*)(yp - C_);
                s0 = fmaf((float)y0[0], w0[0], s0); s1 = fmaf((float)y0[1], w0[1], s1);
                s2 = fmaf((float)y0[2], w0[2], s2); s3 = fmaf((float)y0[3], w0[3], s3);
            }
            if (nloc < N_-1){
                h4v y2 = *(const h4v*)(yp + C_);
                s0 = fmaf((float)y2[0], w2[0], s0); s1 = fmaf((float)y2[1], w2[1], s1);
                s2 = fmaf((float)y2[2], w2[2], s2); s3 = fmaf((float)y2[3], w2[3], s3);
            }
            float4 o;
            o.x = (float)a[0] + s0; o.y = (float)a[1] + s1;
            o.z = (float)a[2] + s2; o.w = (float)a[3] + s3;
            *(float4*)&outp[(size_t)grow*C_ + col0 + c4p] = o;
        }
    }
}

// ---- kv = (1/N) k_rope^T @ v : both operands f16, LDS-transposed, chunk-XOR swizzle ----
__global__ __launch_bounds__(256) void k_kv(const _Float16* __restrict__ krh, const _Float16* __restrict__ yh,
                                            float* __restrict__ kvg){
    __shared__ _Float16 krs[64*128];
    __shared__ _Float16 vs[64*128];
    const int split = blockIdx.x, bh = blockIdx.y;
    const int b = bh >> 3, h = bh & 7;
    const int t = threadIdx.x, lane = t & 63, w = t >> 6;
    const int lrow = lane & 15, lg = lane >> 4;
    f4 acc[4] = {};
    for (int sub=0; sub<4; ++sub){
        const int n0 = split*512 + sub*128;
#pragma unroll
        for (int i=0;i<8;++i){
            int q = i*256 + t;
            int d2 = q & 31, n2 = q >> 5;
            int n = n0 + 2*n2, c = h*64 + 2*d2;
            size_t g0 = (size_t)(b*N_ + n)*C_ + c;
            unsigned int u0 = *(const unsigned int*)&krh[g0];
            unsigned int u1 = *(const unsigned int*)&krh[g0 + C_];
            unsigned int v0 = *(const unsigned int*)&yh[g0];
            unsigned int v1 = *(const unsigned int*)&yh[g0 + C_];
            int chunk = n2 >> 2, j2 = (n2 & 3)*2;
            int pc0 = chunk ^ ((2*d2) & 15);
            int pc1 = pc0 ^ 1;
            *(unsigned int*)&krs[(2*d2)*128 + pc0*8 + j2]   = (u0 & 0xffffu) | (u1 << 16);
            *(unsigned int*)&krs[(2*d2+1)*128 + pc1*8 + j2] = (u0 >> 16) | (u1 & 0xffff0000u);
            *(unsigned int*)&vs[(2*d2)*128 + pc0*8 + j2]    = (v0 & 0xffffu) | (v1 << 16);
            *(unsigned int*)&vs[(2*d2+1)*128 + pc1*8 + j2]  = (v0 >> 16) | (v1 & 0xffff0000u);
        }
        __syncthreads();
#pragma unroll
        for (int ks=0; ks<4; ++ks){
            int cu = ((ks*4 + lg) ^ lrow)*8;
            h8 a = *(const h8*)&krs[(w*16 + lrow)*128 + cu];
#pragma unroll
            for (int ni=0; ni<4; ++ni){
                h8 bv = *(const h8*)&vs[(ni*16 + lrow)*128 + cu];
                acc[ni] = __builtin_amdgcn_mfma_f32_16x16x32_f16(a, bv, acc[ni], 0,0,0);
            }
        }
        __syncthreads();
    }
#pragma unroll
    for (int ni=0; ni<4; ++ni)
#pragma unroll
        for (int rr=0; rr<4; ++rr)
            atomicAdd(&kvg[(size_t)bh*4096 + (w*16 + lg*4 + rr)*64 + ni*16 + lrow],
                      acc[ni][rr] * (1.0f/4096.0f));
}

// ---- kvg f32 [bh][d][e] -> kvTg f16 [bh][e][d] ----
__global__ __launch_bounds__(256) void k_kvmerge(const float* __restrict__ kvg, _Float16* __restrict__ kvTg){
    int bh = blockIdx.x, t = threadIdx.x;
    const float* src = kvg + (size_t)bh*4096;
    _Float16* dst = kvTg + (size_t)bh*4096;
#pragma unroll
    for (int i=0;i<4;++i){
        int q = i*256 + t;
        int e2 = q & 31, d2 = q >> 5;
        float2 a0 = *(const float2*)&src[(2*d2)*64 + 2*e2];
        float2 a1 = *(const float2*)&src[(2*d2+1)*64 + 2*e2];
        *(unsigned int*)&dst[(2*e2)*64 + 2*d2]   = pack2h(a0.x, a1.x);
        *(unsigned int*)&dst[(2*e2+1)*64 + 2*d2] = pack2h(a0.y, a1.y);
    }
}

extern "C" void kernel_launch(void* const* d_in, const int* in_sizes, int n_in,
                              void* d_out, int out_size, void* d_ws, size_t ws_size,
                              hipStream_t stream)
{
    (void)in_sizes; (void)n_in; (void)out_size; (void)ws_size;
    const float* x  = (const float*)d_in[0];
    const float* y  = (const float*)d_in[1];
    const float* Wq = (const float*)d_in[2];
    const float* bq = (const float*)d_in[3];
    const float* Wk = (const float*)d_in[4];
    const float* bk = (const float*)d_in[5];
    const float* lw = (const float*)d_in[6];
    const float* lb = (const float*)d_in[7];

    char* ws = (char*)d_ws;
    float*    cosT = (float*)(ws + OFF_COS);
    float*    sinT = (float*)(ws + OFF_SIN);
    _Float16* krh  = (_Float16*)(ws + OFF_KRH);   // then reused as xh
    _Float16* yh   = (_Float16*)(ws + OFF_YH);
    _Float16* Wqh  = (_Float16*)(ws + OFF_WQH);
    _Float16* Wkh  = (_Float16*)(ws + OFF_WKH);
    float*    ksum = (float*)(ws + OFF_KSUM);
    float*    kvg  = (float*)(ws + OFF_KVG);
    _Float16* kvTg = (_Float16*)(ws + OFF_KVT);
    float*    out  = (float*)d_out;

    hipMemsetAsync(ws + OFF_KSUM, 0, 64*1024 + 1024*1024, stream);
    k_tables<<<dim3(N_), dim3(256), 0, stream>>>(cosT, sinT);
    k_prep_y<<<dim3(8448), dim3(256), 0, stream>>>(y, Wq, Wk, yh, Wqh, Wkh);
    k_gemm<0><<<dim3(4, 512), dim3(256), 0, stream>>>(yh, Wkh, bk, cosT, sinT,
        krh, ksum, nullptr, nullptr, nullptr, nullptr, nullptr, nullptr);
    k_kv<<<dim3(8, 64), dim3(256), 0, stream>>>(krh, yh, kvg);
    k_kvmerge<<<dim3(64), dim3(256), 0, stream>>>(kvg, kvTg);
    k_prep_x<<<dim3(8192), dim3(256), 0, stream>>>(x, krh);   // xh overwrites retired krh
    k_gemm<1><<<dim3(4, 512), dim3(256), 0, stream>>>(krh, Wqh, bq, cosT, sinT,
        nullptr, nullptr, ksum, kvTg, yh, lw, lb, out);
}